// Round 23
// baseline (60.815 us; speedup 1.0000x reference)
//
#include <hip/hip_runtime.h>
#include <hip/hip_bf16.h>
#include <math.h>

#define MDIM 1024
#define QTOT 65536
#define KTOP 16
#define ODIM 256
#define FDIM 512

typedef float f32x4 __attribute__((ext_vector_type(4)));
typedef short s16x8 __attribute__((ext_vector_type(8)));
typedef unsigned u32x4 __attribute__((ext_vector_type(4)));

// pinned single-instruction ops
#define VMIN(a,b)  ({float r_; asm("v_min_f32 %0,%1,%2":"=v"(r_):"v"(a),"v"(b)); r_;})
#define VMAX(a,b)  ({float r_; asm("v_max_f32 %0,%1,%2":"=v"(r_):"v"(a),"v"(b)); r_;})
#define VEXP2(x)   ({float r_; asm("v_exp_f32 %0,%1":"=v"(r_):"v"(x)); r_;})

__device__ __forceinline__ int read_mask(const void* m, int i, bool is8) {
  return is8 ? (int)((const unsigned char*)m)[i] : ((const int*)m)[i];
}

__device__ __forceinline__ unsigned pack2(float lo, float hi) {
  __hip_bfloat162 h = __float22bfloat162_rn(make_float2(lo, hi));
  unsigned u;
  __builtin_memcpy(&u, &h, sizeof(u));
  return u;
}

// sort networks on local arrays
#define CEx(A,i,j) { float mn_ = VMIN(A[i], A[j]); float mx_ = VMAX(A[i], A[j]); A[i] = mn_; A[j] = mx_; }
#define SORT8(A) \
  CEx(A,0,1) CEx(A,2,3) CEx(A,4,5) CEx(A,6,7) \
  CEx(A,0,2) CEx(A,1,3) CEx(A,4,6) CEx(A,5,7) \
  CEx(A,1,2) CEx(A,5,6) \
  CEx(A,0,4) CEx(A,1,5) CEx(A,2,6) CEx(A,3,7) \
  CEx(A,2,4) CEx(A,3,5) \
  CEx(A,1,2) CEx(A,3,4) CEx(A,5,6)
#define CLEAN8(A) \
  CEx(A,0,4) CEx(A,1,5) CEx(A,2,6) CEx(A,3,7) \
  CEx(A,0,2) CEx(A,1,3) CEx(A,4,6) CEx(A,5,7) \
  CEx(A,0,1) CEx(A,2,3) CEx(A,4,5) CEx(A,6,7)
#define CLEAN16(A) \
  CEx(A,0,8) CEx(A,1,9) CEx(A,2,10) CEx(A,3,11) CEx(A,4,12) CEx(A,5,13) CEx(A,6,14) CEx(A,7,15) \
  CEx(A,0,4) CEx(A,1,5) CEx(A,2,6)  CEx(A,3,7)  CEx(A,8,12) CEx(A,9,13) CEx(A,10,14) CEx(A,11,15) \
  CEx(A,0,2) CEx(A,1,3) CEx(A,4,6)  CEx(A,5,7)  CEx(A,8,10) CEx(A,9,11) CEx(A,12,14) CEx(A,13,15) \
  CEx(A,0,1) CEx(A,2,3) CEx(A,4,5)  CEx(A,6,7)  CEx(A,8,9)  CEx(A,10,11) CEx(A,12,13) CEx(A,14,15)

// ---------------- kernel 0: W fp32 -> bf16 fragment-layout prepass ----------
// Wb[(cg*16+s)*64 + l]: 8 bf16 = W[col = cg*16 + (l&15)][s*32 + (l>>4)*8 ..+8]
__global__ __launch_bounds__(256) void wconv_kernel(
    const float* __restrict__ W, u32x4* __restrict__ Wb)
{
  int slot = blockIdx.x * 256 + threadIdx.x;   // 0..16383
  int cg = slot >> 10;
  int rem = slot & 1023;
  int s = rem >> 6, l = rem & 63;
  int col = cg * 16 + (l & 15);
  int kk = s * 32 + (l >> 4) * 8;
  const float4* p = (const float4*)(W + (size_t)col * FDIM + kk);
  float4 a = p[0], b = p[1];
  u32x4 u0;
  u0[0] = pack2(a.x, a.y); u0[1] = pack2(a.z, a.w);
  u0[2] = pack2(b.x, b.y); u0[3] = pack2(b.z, b.w);
  Wb[(size_t)(cg * 16 + s) * 64 + l] = u0;
}

// ---------------- fused kernel: top-16 -> RBF -> projection ----------------
// grid: QTOT/64 = 1024 blocks x 512 threads (8 waves), 2 blocks/CU (71 KB LDS).
// Phase 1: one query per lane; wave w scans slice w*G..(w+1)*G with uniform
//   (broadcast) ds_reads, keeping only a SORTED-8 per lane (11.75 ops/cand).
//   Self not checked in scan (its d' = -Q is its slice's minimum; dropped at
//   merge via +1-offset read). Wave 0 merges the 8 lists; if any slice's 8th-
//   smallest < final 16th (may have discarded a top-16 member), the block
//   reruns an exact top-16 path (~12% of blocks).
// Phase 2: gen full 64-row A tile (unioned LDS). Phase 3: MFMA, 2 B-loads/s
//   feed 8 MFMAs (acc[4][2]). Clean scalar stores (WRITE-exact pattern).
constexpr double SPd = 24.0 / 31.0;
constexpr double SP2d = SPd * SPd;
constexpr float ALPHA = (float)(-(SP2d / (SP2d + 1e-8)) * 1.4426950408889634);
constexpr float INV_SP = (float)(1.0 / SPd);

__device__ __forceinline__ void gen_cell(u32x4* Ab, int rf, int rowlo, int s, float d0) {
  float d = (d0 < 0.f) ? 1.0e9f : d0;   // sentinel -> rbf == 0
  float u = d * INV_SP;
  float C1 = (-2.0f * ALPHA) * u;
  float C0 = ALPHA * u * u;
  #pragma unroll
  for (int c8 = 0; c8 < 4; ++c8) {
    u32x4 ch;
    #pragma unroll
    for (int q = 0; q < 4; ++q) {
      const int j0 = c8 * 8 + q * 2;
      float e0 = VEXP2(fmaf(C1, (float)j0,       C0) + ALPHA * (float)(j0 * j0));
      float e1 = VEXP2(fmaf(C1, (float)(j0 + 1), C0) + ALPHA * (float)((j0 + 1) * (j0 + 1)));
      ch[q] = pack2(e0, e1);
    }
    Ab[rf * 1040 + s * 65 + c8 * 16 + rowlo] = ch;
  }
}

__global__ __launch_bounds__(512, 6) void fused_kernel(
    const float* __restrict__ coords, const void* __restrict__ mask,
    const u32x4* __restrict__ Wb, float* __restrict__ out)
{
  // LDS union: phase 1 = pts float4[1024] (16K) + posof short[1024] (2K) +
  //   ST at 18432 (main: 512*9*4 = 18.4K; fallback: 512*17*4 = 34.8K);
  // phase 2/3 = A tile u32x4[4][1040] (66560B). Union = 66560B.
  __shared__ __align__(16) char raw[66560];
  __shared__ float dvals[64][17];
  __shared__ int s_cnt;
  __shared__ int s_is8;
  __shared__ int s_fb;

  float4* pts = (float4*)raw;
  short* posof = (short*)(raw + 16384);
  float* ST = (float*)(raw + 18432);
  u32x4* Ab = (u32x4*)raw;

  const int tid = threadIdx.x;      // 0..511
  const int lane = tid & 63;
  const int wv = tid >> 6;          // 0..7
  const int bid = blockIdx.x;
  const int batch = bid >> 4;       // 16 blocks per batch (64 queries each)
  const int qchunk = bid & 15;

  if (tid == 0) { s_cnt = 0; s_is8 = 0; s_fb = 0; }
  __syncthreads();
  { // mask dtype detection: int32 0/1 words vs packed int8 bools
    unsigned w = ((const unsigned*)mask)[tid & 255];
    if (w > 1u) atomicOr(&s_is8, 1);
  }
  __syncthreads();
  const bool is8 = (s_is8 != 0);

  const float* cb = coords + (size_t)batch * MDIM * 3;
  const int mbase = batch * MDIM;

  // compact valid atoms into LDS: (x,y,z,|p|^2)
  #pragma unroll
  for (int r = 0; r < 2; ++r) {
    int a = r * 512 + tid;
    int v = read_mask(mask, mbase + a, is8);
    float x = cb[a*3+0], y = cb[a*3+1], z = cb[a*3+2];
    float S = fmaf(z, z, fmaf(y, y, x * x));
    unsigned long long bal = __ballot(v != 0);
    int base = 0;
    if (lane == 0) base = atomicAdd(&s_cnt, __popcll(bal));
    base = __shfl(base, 0);
    int pos = base + __popcll(bal & ((1ull << lane) - 1ull));
    if (v) {
      float4 p; p.x = x; p.y = y; p.z = z; p.w = S;
      pts[pos] = p;
    }
    posof[a] = (short)(v ? pos : -1);
  }
  __syncthreads();
  const int cnt = s_cnt;
  const int cntP = (cnt + 63) & ~63;   // pad to x64 (<= MDIM)
  for (int i = cnt + tid; i < cntP; i += 512) {
    float4 p; p.x = 0.f; p.y = 0.f; p.z = 0.f; p.w = 3.0e38f;  // d' = +huge
    pts[i] = p;
  }
  __syncthreads();

  // ---- phase 1: one query per lane; wave scans its candidate slice ----
  const int qlocal = qchunk * 64 + lane;     // this lane's query
  const float qx = cb[qlocal*3+0], qy = cb[qlocal*3+1], qz = cb[qlocal*3+2];
  const float Q = fmaf(qz, qz, fmaf(qy, qy, qx * qx));
  const float m2x = -2.0f * qx, m2y = -2.0f * qy, m2z = -2.0f * qz;
  const int selfpos = posof[qlocal];
  const int G = cntP >> 3;                   // slice size (multiple of 8)
  const int sbase = wv * G;

  float t8[8];
  #pragma unroll
  for (int i = 0; i < 8; ++i) t8[i] = 3.0e38f;

  for (int b = 0; b < G; b += 8) {
    float s[8];
    #pragma unroll
    for (int i = 0; i < 8; ++i) {
      float4 p = pts[sbase + b + i];         // wave-uniform -> LDS broadcast
      // d' = |p|^2 - 2 q.p (= d^2 - Q, order-preserving); self scans too
      s[i] = fmaf(p.z, m2z, fmaf(p.y, m2y, fmaf(p.x, m2x, p.w)));
    }
    SORT8(s)
    // keep 8 smallest of (t8 ∪ s): bitonic low-half + clean-8
    float m[8];
    #pragma unroll
    for (int i = 0; i < 8; ++i) m[i] = VMIN(t8[i], s[7 - i]);
    CLEAN8(m)
    #pragma unroll
    for (int i = 0; i < 8; ++i) t8[i] = m[i];
  }

  // stage this lane's sorted-8 (stride 9 -> conflict-free banks)
  {
    float* dst = ST + (wv * 64 + lane) * 9;
    #pragma unroll
    for (int i = 0; i < 8; ++i) dst[i] = t8[i];
  }
  __syncthreads();

  // wave 0: merge the 8 slice-lists per query (lane = query)
  if (wv == 0) {
    // slice containing self (its min = self's d' = -Q; drop via +1 shift)
    int selfslice = 0;
    if (selfpos >= 0) {
      #pragma unroll
      for (int sl = 1; sl < 8; ++sl) selfslice += (selfpos >= sl * G) ? 1 : 0;
    } else {
      selfslice = -1;
    }
    float t16[16];
    float bmin;
    {
      const float* ls = ST + lane * 9;
      int sh = (selfslice == 0) ? 1 : 0;
      #pragma unroll
      for (int i = 0; i < 7; ++i) t16[i] = ls[i + sh];
      t16[7] = sh ? 3.0e38f : ls[7];
      #pragma unroll
      for (int i = 8; i < 16; ++i) t16[i] = 3.0e38f;
      bmin = ls[7];
    }
    for (int sl = 1; sl < 8; ++sl) {
      const float* ls = ST + (sl * 64 + lane) * 9;
      int sh = (selfslice == sl) ? 1 : 0;
      float o[8];
      #pragma unroll
      for (int i = 0; i < 7; ++i) o[i] = ls[i + sh];
      o[7] = sh ? 3.0e38f : ls[7];
      bmin = VMIN(bmin, ls[7]);
      // merge sorted-8 o into sorted-16 t16 (keep 16 smallest)
      #pragma unroll
      for (int i = 0; i < 8; ++i) t16[8 + i] = VMIN(t16[8 + i], o[7 - i]);
      CLEAN16(t16)
    }
    // exactness: any slice may have discarded a true top-16 member?
    if (bmin < t16[15]) atomicOr(&s_fb, 1);
    int mq = read_mask(mask, mbase + qlocal, is8);
    #pragma unroll
    for (int i = 0; i < 16; ++i) {
      float v = t16[i];
      float d = (v > 1.0e37f) ? 24.0f : sqrtf(fmaxf(v + Q, 1e-12f)); // pad -> MAX_DIST
      dvals[lane][i] = mq ? d : -1.0f;   // -1 sentinel => zero output row
    }
  }
  __syncthreads();

  // ---- exact fallback (rare, ~12% of blocks): per-lane top-16 redo ----
  if (s_fb != 0) {
    float t[16];
    #pragma unroll
    for (int i = 0; i < 16; ++i) t[i] = 3.0e38f;
    for (int b = 0; b < G; b += 8) {
      float s[8];
      #pragma unroll
      for (int i = 0; i < 8; ++i) {
        const int idx = sbase + b + i;
        float4 p = pts[idx];
        float d = fmaf(p.z, m2z, fmaf(p.y, m2y, fmaf(p.x, m2x, p.w)));
        s[i] = (idx == selfpos) ? 3.0e38f : d;  // exclude self exactly
      }
      SORT8(s)
      #pragma unroll
      for (int i = 0; i < 8; ++i) t[8 + i] = VMIN(t[8 + i], s[7 - i]);
      CLEAN16(t)
    }
    {
      float* dst = ST + (wv * 64 + lane) * 17;
      #pragma unroll
      for (int i = 0; i < 16; ++i) dst[i] = t[i];
    }
    __syncthreads();
    if (wv == 0) {
      float m0[16];
      const float* l0 = ST + lane * 17;
      #pragma unroll
      for (int i = 0; i < 16; ++i) m0[i] = l0[i];
      for (int sl = 1; sl < 8; ++sl) {
        const float* ls = ST + (sl * 64 + lane) * 17;
        float o[16], m[16];
        #pragma unroll
        for (int i = 0; i < 16; ++i) o[i] = ls[i];
        #pragma unroll
        for (int i = 0; i < 16; ++i) m[i] = VMIN(m0[i], o[15 - i]);
        CLEAN16(m)
        #pragma unroll
        for (int i = 0; i < 16; ++i) m0[i] = m[i];
      }
      int mq = read_mask(mask, mbase + qlocal, is8);
      #pragma unroll
      for (int i = 0; i < 16; ++i) {
        float v = m0[i];
        float d = (v > 1.0e37f) ? 24.0f : sqrtf(fmaxf(v + Q, 1e-12f));
        dvals[lane][i] = mq ? d : -1.0f;
      }
    }
    __syncthreads();
  }

  // ---- phase 2: RBF A-gen, full 64-row tile (2 cells/thread) ----
  #pragma unroll
  for (int i = 0; i < 2; ++i) {
    int cellid = tid + 512 * i;          // 0..1023
    int row = cellid >> 4, slot = cellid & 15;
    gen_cell(Ab, row >> 4, row & 15, slot, dvals[row][slot]);
  }
  __syncthreads();

  // ---- phase 3: MFMA 64 rows x 256 cols; wave owns col-groups {wv, 8+wv};
  //      2 B-loads per s feed 8 MFMAs (acc[4][2]) ----
  f32x4 acc[4][2];
  #pragma unroll
  for (int rf = 0; rf < 4; ++rf)
    #pragma unroll
    for (int e = 0; e < 2; ++e) acc[rf][e] = (f32x4){0.f, 0.f, 0.f, 0.f};

  u32x4 bcur[2], bnxt[2];
  #pragma unroll
  for (int e = 0; e < 2; ++e)
    bcur[e] = Wb[(size_t)((e * 8 + wv) * 16) * 64 + lane];

  #pragma unroll
  for (int s = 0; s < 16; ++s) {
    if (s < 15) {
      #pragma unroll
      for (int e = 0; e < 2; ++e)
        bnxt[e] = Wb[(size_t)((e * 8 + wv) * 16 + s + 1) * 64 + lane];
    }
    s16x8 a[4], b[2];
    #pragma unroll
    for (int rf = 0; rf < 4; ++rf) {
      u32x4 ra = Ab[rf * 1040 + s * 65 + lane];
      __builtin_memcpy(&a[rf], &ra, sizeof(ra));
    }
    #pragma unroll
    for (int e = 0; e < 2; ++e) __builtin_memcpy(&b[e], &bcur[e], sizeof(u32x4));
    #pragma unroll
    for (int rf = 0; rf < 4; ++rf)
      #pragma unroll
      for (int e = 0; e < 2; ++e)
        acc[rf][e] = __builtin_amdgcn_mfma_f32_16x16x32_bf16(a[rf], b[e], acc[rf][e], 0, 0, 0);
    #pragma unroll
    for (int e = 0; e < 2; ++e) bcur[e] = bnxt[e];
  }

  // D layout: col = lane&15, row = (lane>>4)*4 + reg. Clean scalar pattern
  // (16 adjacent lanes = 64B runs) — WRITE_SIZE-exact across rounds.
  const int qbase = mbase + qchunk * 64;
  const int rb_ = (lane >> 4) * 4;
  #pragma unroll
  for (int rf = 0; rf < 4; ++rf) {
    #pragma unroll
    for (int e = 0; e < 2; ++e) {
      const int col = (e * 8 + wv) * 16 + (lane & 15);
      #pragma unroll
      for (int r = 0; r < 4; ++r)
        out[(size_t)(qbase + rf * 16 + rb_ + r) * ODIM + col] = acc[rf][e][r];
    }
  }
}

extern "C" void kernel_launch(void* const* d_in, const int* in_sizes, int n_in,
                              void* d_out, int out_size, void* d_ws, size_t ws_size,
                              hipStream_t stream) {
  const float* coords = (const float*)d_in[0];
  const void* mask = d_in[1];
  const float* W = (const float*)d_in[2];
  float* out = (float*)d_out;
  u32x4* Wb = (u32x4*)d_ws;   // 256 KB bf16 W fragments

  hipLaunchKernelGGL(wconv_kernel, dim3(64), dim3(256), 0, stream, W, Wb);
  hipLaunchKernelGGL(fused_kernel, dim3(QTOT / 64), dim3(512), 0, stream,
                     coords, mask, Wb, out);
}

// Round 24
// 52.219 us; speedup vs baseline: 1.1646x; 1.1646x over previous
//
#include <hip/hip_runtime.h>
#include <hip/hip_bf16.h>
#include <math.h>

#define MDIM 1024
#define QTOT 65536
#define KTOP 16
#define ODIM 256
#define FDIM 512

typedef float f32x4 __attribute__((ext_vector_type(4)));
typedef short s16x8 __attribute__((ext_vector_type(8)));
typedef unsigned u32x4 __attribute__((ext_vector_type(4)));

// pinned single-instruction ops
#define VMIN(a,b)  ({float r_; asm("v_min_f32 %0,%1,%2":"=v"(r_):"v"(a),"v"(b)); r_;})
#define VMAX(a,b)  ({float r_; asm("v_max_f32 %0,%1,%2":"=v"(r_):"v"(a),"v"(b)); r_;})
#define VEXP2(x)   ({float r_; asm("v_exp_f32 %0,%1":"=v"(r_):"v"(x)); r_;})

__device__ __forceinline__ int read_mask(const void* m, int i, bool is8) {
  return is8 ? (int)((const unsigned char*)m)[i] : ((const int*)m)[i];
}

__device__ __forceinline__ unsigned pack2(float lo, float hi) {
  __hip_bfloat162 h = __float22bfloat162_rn(make_float2(lo, hi));
  unsigned u;
  __builtin_memcpy(&u, &h, sizeof(u));
  return u;
}

// sort networks on local arrays
#define CEx(A,i,j) { float mn_ = VMIN(A[i], A[j]); float mx_ = VMAX(A[i], A[j]); A[i] = mn_; A[j] = mx_; }
#define SORT8(A) \
  CEx(A,0,1) CEx(A,2,3) CEx(A,4,5) CEx(A,6,7) \
  CEx(A,0,2) CEx(A,1,3) CEx(A,4,6) CEx(A,5,7) \
  CEx(A,1,2) CEx(A,5,6) \
  CEx(A,0,4) CEx(A,1,5) CEx(A,2,6) CEx(A,3,7) \
  CEx(A,2,4) CEx(A,3,5) \
  CEx(A,1,2) CEx(A,3,4) CEx(A,5,6)
#define CLEAN8(A) \
  CEx(A,0,4) CEx(A,1,5) CEx(A,2,6) CEx(A,3,7) \
  CEx(A,0,2) CEx(A,1,3) CEx(A,4,6) CEx(A,5,7) \
  CEx(A,0,1) CEx(A,2,3) CEx(A,4,5) CEx(A,6,7)
#define CLEAN16(A) \
  CEx(A,0,8) CEx(A,1,9) CEx(A,2,10) CEx(A,3,11) CEx(A,4,12) CEx(A,5,13) CEx(A,6,14) CEx(A,7,15) \
  CEx(A,0,4) CEx(A,1,5) CEx(A,2,6)  CEx(A,3,7)  CEx(A,8,12) CEx(A,9,13) CEx(A,10,14) CEx(A,11,15) \
  CEx(A,0,2) CEx(A,1,3) CEx(A,4,6)  CEx(A,5,7)  CEx(A,8,10) CEx(A,9,11) CEx(A,12,14) CEx(A,13,15) \
  CEx(A,0,1) CEx(A,2,3) CEx(A,4,5)  CEx(A,6,7)  CEx(A,8,9)  CEx(A,10,11) CEx(A,12,13) CEx(A,14,15)

// ---------------- kernel 0: W fp32 -> bf16 fragment-layout prepass ----------
// Wb[(cg*16+s)*64 + l]: 8 bf16 = W[col = cg*16 + (l&15)][s*32 + (l>>4)*8 ..+8]
__global__ __launch_bounds__(256) void wconv_kernel(
    const float* __restrict__ W, u32x4* __restrict__ Wb)
{
  int slot = blockIdx.x * 256 + threadIdx.x;   // 0..16383
  int cg = slot >> 10;
  int rem = slot & 1023;
  int s = rem >> 6, l = rem & 63;
  int col = cg * 16 + (l & 15);
  int kk = s * 32 + (l >> 4) * 8;
  const float4* p = (const float4*)(W + (size_t)col * FDIM + kk);
  float4 a = p[0], b = p[1];
  u32x4 u0;
  u0[0] = pack2(a.x, a.y); u0[1] = pack2(a.z, a.w);
  u0[2] = pack2(b.x, b.y); u0[3] = pack2(b.z, b.w);
  Wb[(size_t)(cg * 16 + s) * 64 + l] = u0;
}

// ---------------- fused kernel: top-16 -> RBF -> projection ----------------
// grid: QTOT/64 = 1024 blocks x 512 threads (8 waves), LDS 71 KB -> 2 blocks/CU.
// Phase 1: strided-part selection; self NOT excluded during scan (its d' = -Q
//   is provably the owning part's minimum) -> owner shift-drops t8[0] after
//   the loop; bound (pre-shift) + exact fallback preserve exactness.
// Phase 2: single gen of the full 64-row A tile (unioned with pts).
// Phase 3: one barrier; per s: 2 B-loads serve 8 MFMAs (acc[4][2]) -> B-L2
//   traffic halved vs per-half loops. Clean scalar stores.
constexpr double SPd = 24.0 / 31.0;
constexpr double SP2d = SPd * SPd;
constexpr float ALPHA = (float)(-(SP2d / (SP2d + 1e-8)) * 1.4426950408889634);
constexpr float INV_SP = (float)(1.0 / SPd);

__device__ __forceinline__ void gen_cell(u32x4* Ab, int rf, int rowlo, int s, float d0) {
  float d = (d0 < 0.f) ? 1.0e9f : d0;   // sentinel -> rbf == 0
  float u = d * INV_SP;
  float C1 = (-2.0f * ALPHA) * u;
  float C0 = ALPHA * u * u;
  #pragma unroll
  for (int c8 = 0; c8 < 4; ++c8) {
    u32x4 ch;
    #pragma unroll
    for (int q = 0; q < 4; ++q) {
      const int j0 = c8 * 8 + q * 2;
      float e0 = VEXP2(fmaf(C1, (float)j0,       C0) + ALPHA * (float)(j0 * j0));
      float e1 = VEXP2(fmaf(C1, (float)(j0 + 1), C0) + ALPHA * (float)((j0 + 1) * (j0 + 1)));
      ch[q] = pack2(e0, e1);
    }
    Ab[rf * 1040 + s * 65 + c8 * 16 + rowlo] = ch;
  }
}

__global__ __launch_bounds__(512, 6) void fused_kernel(
    const float* __restrict__ coords, const void* __restrict__ mask,
    const u32x4* __restrict__ Wb, float* __restrict__ out)
{
  // LDS union: phase 1 = pts float4[1024] (16K) + posof short[1024] (2K);
  //            phase 2/3 = A tile u32x4[4][1040] (66560B). Union = 66560B.
  __shared__ __align__(16) char raw[66560];
  __shared__ float dvals[64][17];
  __shared__ int s_cnt;
  __shared__ int s_is8;

  float4* pts = (float4*)raw;
  short* posof = (short*)(raw + 16384);
  u32x4* Ab = (u32x4*)raw;

  const int tid = threadIdx.x;      // 0..511
  const int lane = tid & 63;
  const int wv = tid >> 6;          // 0..7
  const int bid = blockIdx.x;
  const int batch = bid >> 4;       // 16 blocks per batch (64 queries each)
  const int qchunk = bid & 15;

  if (tid == 0) { s_cnt = 0; s_is8 = 0; }
  __syncthreads();
  { // mask dtype detection: int32 0/1 words vs packed int8 bools
    unsigned w = ((const unsigned*)mask)[tid & 255];
    if (w > 1u) atomicOr(&s_is8, 1);
  }
  __syncthreads();
  const bool is8 = (s_is8 != 0);

  const float* cb = coords + (size_t)batch * MDIM * 3;
  const int mbase = batch * MDIM;

  // compact valid atoms into LDS: (x,y,z,|p|^2)
  #pragma unroll
  for (int r = 0; r < 2; ++r) {
    int a = r * 512 + tid;
    int v = read_mask(mask, mbase + a, is8);
    float x = cb[a*3+0], y = cb[a*3+1], z = cb[a*3+2];
    float S = fmaf(z, z, fmaf(y, y, x * x));
    unsigned long long bal = __ballot(v != 0);
    int base = 0;
    if (lane == 0) base = atomicAdd(&s_cnt, __popcll(bal));
    base = __shfl(base, 0);
    int pos = base + __popcll(bal & ((1ull << lane) - 1ull));
    if (v) {
      float4 p; p.x = x; p.y = y; p.z = z; p.w = S;
      pts[pos] = p;
    }
    posof[a] = (short)(v ? pos : -1);
  }
  __syncthreads();
  const int cnt = s_cnt;
  const int cntP = (cnt + 63) & ~63;   // pad to x64 (<= MDIM)
  for (int i = cnt + tid; i < cntP; i += 512) {
    float4 p; p.x = 0.f; p.y = 0.f; p.z = 0.f; p.w = 3.0e38f;  // d' = +huge
    pts[i] = p;
  }
  __syncthreads();

  // 8 lanes per query: lane = qi + 8*part
  const int qi = lane & 7;
  const int part = lane >> 3;
  const int qlo = wv * 8 + qi;
  const int qlocal = qchunk * 64 + qlo;
  const float qx = cb[qlocal*3+0], qy = cb[qlocal*3+1], qz = cb[qlocal*3+2];
  const float Q = fmaf(qz, qz, fmaf(qy, qy, qx * qx));
  const float m2x = -2.0f * qx, m2y = -2.0f * qy, m2z = -2.0f * qz;
  const int selfpos = posof[qlocal];
  // part p owns idx = 8k + p; self matches only if (selfpos&7)==part
  const bool own = (selfpos >= 0) && ((selfpos & 7) == part);
  const int selfk = own ? (selfpos >> 3) : -1;
  const int ngroups = cntP >> 6;
  const float4* pbase = pts + part;

  float t8[8];
  #pragma unroll
  for (int i = 0; i < 8; ++i) t8[i] = 3.0e38f;

  for (int g = 0; g < ngroups; ++g) {
    float s[8];
    #pragma unroll
    for (int i = 0; i < 8; ++i) {
      float4 p = pbase[(size_t)(g * 8 + i) * 8];   // ds offset: g*1024 + i*128
      // d' = |p|^2 - 2 q.p  (= d^2 - Q, order-preserving); self scans too
      s[i] = fmaf(p.z, m2z, fmaf(p.y, m2y, fmaf(p.x, m2x, p.w)));
    }
    SORT8(s)
    // keep 8 smallest of (t8 ∪ s): bitonic low-half + clean-8
    float m[8];
    #pragma unroll
    for (int i = 0; i < 8; ++i) m[i] = VMIN(t8[i], s[7 - i]);
    CLEAN8(m)
    #pragma unroll
    for (int i = 0; i < 8; ++i) t8[i] = m[i];
  }
  const float bound = t8[7];   // all discarded values >= bound (pre-shift)
  // owner part: self's d' (= -Q, the part minimum) sits at t8[0]; drop it
  if (own) {
    #pragma unroll
    for (int i = 0; i < 7; ++i) t8[i] = t8[i + 1];
    t8[7] = 3.0e38f;
  }

  // ^8: full-merge two sorted-8 -> sorted-16 (bitonic split + two clean-8)
  float t[16];
  {
    float o[8], L[8], H[8];
    #pragma unroll
    for (int i = 0; i < 8; ++i) o[i] = __shfl(t8[i], lane ^ 8);
    #pragma unroll
    for (int i = 0; i < 8; ++i) { L[i] = VMIN(t8[i], o[7 - i]); H[i] = VMAX(t8[i], o[7 - i]); }
    CLEAN8(L)
    CLEAN8(H)
    #pragma unroll
    for (int i = 0; i < 8; ++i) { t[i] = L[i]; t[8 + i] = H[i]; }
  }
  // ^16, ^32: keep 16 smallest of two sorted-16
  #pragma unroll
  for (int stepi = 0; stepi < 2; ++stepi) {
    const int step = 16 << stepi;
    float o[16], m[16];
    #pragma unroll
    for (int i = 0; i < 16; ++i) o[i] = __shfl(t[i], lane ^ step);
    #pragma unroll
    for (int i = 0; i < 16; ++i) m[i] = VMIN(t[i], o[15 - i]);
    CLEAN16(m)
    #pragma unroll
    for (int i = 0; i < 16; ++i) t[i] = m[i];
  }

  // exactness check: if any part may have discarded a true top-16 member,
  // redo this wave's queries with the exact 16-deep path (rare).
  if (__ballot(bound < t[15]) != 0ull) {
    #pragma unroll
    for (int i = 0; i < 16; ++i) t[i] = 3.0e38f;
    for (int g = 0; g < ngroups; ++g) {
      float s[8];
      #pragma unroll
      for (int i = 0; i < 8; ++i) {
        float4 p = pbase[(size_t)(g * 8 + i) * 8];
        float d = fmaf(p.z, m2z, fmaf(p.y, m2y, fmaf(p.x, m2x, p.w)));
        s[i] = (g * 8 + i == selfk) ? 3.0e38f : d;   // exclude self exactly
      }
      SORT8(s)
      #pragma unroll
      for (int i = 0; i < 8; ++i) t[8 + i] = VMIN(t[8 + i], s[7 - i]);
      CLEAN16(t)
    }
    #pragma unroll
    for (int stepi = 0; stepi < 3; ++stepi) {
      const int step = 8 << stepi;
      float o[16], m[16];
      #pragma unroll
      for (int i = 0; i < 16; ++i) o[i] = __shfl(t[i], lane ^ step);
      #pragma unroll
      for (int i = 0; i < 16; ++i) m[i] = VMIN(t[i], o[15 - i]);
      CLEAN16(m)
      #pragma unroll
      for (int i = 0; i < 16; ++i) t[i] = m[i];
    }
  }

  if (part == 0) {
    int mq = read_mask(mask, mbase + qlocal, is8);
    #pragma unroll
    for (int i = 0; i < 16; ++i) {
      float v = t[i];
      float d = (v > 1.0e37f) ? 24.0f : sqrtf(fmaxf(v + Q, 1e-12f)); // pad -> MAX_DIST
      dvals[qlo][i] = mq ? d : -1.0f;   // -1 sentinel => zero output row
    }
  }
  __syncthreads();   // dvals ready; pts/posof dead -> LDS reused as A tile

  // ---- phase 2: RBF A-gen, full 64-row tile (2 cells/thread) ----
  #pragma unroll
  for (int i = 0; i < 2; ++i) {
    int cellid = tid + 512 * i;          // 0..1023
    int row = cellid >> 4, slot = cellid & 15;
    gen_cell(Ab, row >> 4, row & 15, slot, dvals[row][slot]);
  }
  __syncthreads();

  // ---- phase 3: MFMA 64 rows x 256 cols; wave owns col-groups {wv, 8+wv};
  //      2 B-loads per s feed 8 MFMAs (acc[4][2]) ----
  f32x4 acc[4][2];
  #pragma unroll
  for (int rf = 0; rf < 4; ++rf)
    #pragma unroll
    for (int e = 0; e < 2; ++e) acc[rf][e] = (f32x4){0.f, 0.f, 0.f, 0.f};

  u32x4 bcur[2], bnxt[2];
  #pragma unroll
  for (int e = 0; e < 2; ++e)
    bcur[e] = Wb[(size_t)((e * 8 + wv) * 16) * 64 + lane];

  #pragma unroll
  for (int s = 0; s < 16; ++s) {
    if (s < 15) {
      #pragma unroll
      for (int e = 0; e < 2; ++e)
        bnxt[e] = Wb[(size_t)((e * 8 + wv) * 16 + s + 1) * 64 + lane];
    }
    s16x8 a[4], b[2];
    #pragma unroll
    for (int rf = 0; rf < 4; ++rf) {
      u32x4 ra = Ab[rf * 1040 + s * 65 + lane];
      __builtin_memcpy(&a[rf], &ra, sizeof(ra));
    }
    #pragma unroll
    for (int e = 0; e < 2; ++e) __builtin_memcpy(&b[e], &bcur[e], sizeof(u32x4));
    #pragma unroll
    for (int rf = 0; rf < 4; ++rf)
      #pragma unroll
      for (int e = 0; e < 2; ++e)
        acc[rf][e] = __builtin_amdgcn_mfma_f32_16x16x32_bf16(a[rf], b[e], acc[rf][e], 0, 0, 0);
    #pragma unroll
    for (int e = 0; e < 2; ++e) bcur[e] = bnxt[e];
  }

  // D layout: col = lane&15, row = (lane>>4)*4 + reg. Clean scalar pattern
  // (16 adjacent lanes = 64B runs) — WRITE_SIZE-exact across rounds.
  const int qbase = mbase + qchunk * 64;
  const int rb_ = (lane >> 4) * 4;
  #pragma unroll
  for (int rf = 0; rf < 4; ++rf) {
    #pragma unroll
    for (int e = 0; e < 2; ++e) {
      const int col = (e * 8 + wv) * 16 + (lane & 15);
      #pragma unroll
      for (int r = 0; r < 4; ++r)
        out[(size_t)(qbase + rf * 16 + rb_ + r) * ODIM + col] = acc[rf][e][r];
    }
  }
}

extern "C" void kernel_launch(void* const* d_in, const int* in_sizes, int n_in,
                              void* d_out, int out_size, void* d_ws, size_t ws_size,
                              hipStream_t stream) {
  const float* coords = (const float*)d_in[0];
  const void* mask = d_in[1];
  const float* W = (const float*)d_in[2];
  float* out = (float*)d_out;
  u32x4* Wb = (u32x4*)d_ws;   // 256 KB bf16 W fragments

  hipLaunchKernelGGL(wconv_kernel, dim3(64), dim3(256), 0, stream, W, Wb);
  hipLaunchKernelGGL(fused_kernel, dim3(QTOT / 64), dim3(512), 0, stream,
                     coords, mask, Wb, out);
}